// Round 2
// baseline (2118.635 us; speedup 1.0000x reference)
//
#include <hip/hip_runtime.h>
#include <stdint.h>
#include <math.h>

#define LAY 24
#define NTOK 576
#define DIM 4096
#define TTXT 128
#define REDD 1024
#define FOCUSL 22

typedef unsigned int u32;
typedef unsigned short u16;
typedef float f32x4 __attribute__((ext_vector_type(4)));
typedef short bf16x8 __attribute__((ext_vector_type(8)));
typedef u16 u16x4 __attribute__((ext_vector_type(4)));

__device__ __forceinline__ u16 f2bf(float f) {
  u32 u = __builtin_bit_cast(u32, f);
  u32 r = u + 0x7fffu + ((u >> 16) & 1u);
  return (u16)(r >> 16);
}
__device__ __forceinline__ float sigm(float x) { return 1.0f / (1.0f + expf(-x)); }

// ---------------- text conditioning ----------------
__global__ void k_text_colmean(const float* __restrict__ tf, float* __restrict__ tmean) {
  int c = blockIdx.x * 256 + threadIdx.x;
  float s = 0.f;
  for (int r = 0; r < TTXT; r++) s += tf[(size_t)r * DIM + c];
  tmean[c] = s * (1.0f / TTXT);
}

__global__ void k_text_ln(const float* __restrict__ tmean, float* __restrict__ tg) {
  __shared__ float red[256];
  int t = threadIdx.x;
  float x[16]; float s = 0.f;
  for (int i = 0; i < 16; i++) { x[i] = tmean[i * 256 + t]; s += x[i]; }
  red[t] = s; __syncthreads();
  for (int o = 128; o; o >>= 1) { if (t < o) red[t] += red[t + o]; __syncthreads(); }
  float mean = red[0] / DIM; __syncthreads();
  float q = 0.f;
  for (int i = 0; i < 16; i++) { float d = x[i] - mean; q += d * d; }
  red[t] = q; __syncthreads();
  for (int o = 128; o; o >>= 1) { if (t < o) red[t] += red[t + o]; __syncthreads(); }
  float var = red[0] / DIM;
  float rinv = 1.0f / sqrtf(var + 1e-5f);
  for (int i = 0; i < 16; i++) tg[i * 256 + t] = (x[i] - mean) * rinv;
}

// ---------------- pass A: group means + bf16 conversion ----------------
// grid = 24 (l) * 4 (dc) * 3 (a) = 288 blocks, 256 thr; group g = a*3+c, c=(nn/8)%3
__global__ void k_pass_a(const float* __restrict__ x, u16* __restrict__ xb,
                         float* __restrict__ gm) {
  int bid = blockIdx.x;
  int a = bid % 3, dc = (bid / 3) & 3, l = bid / 12;
  int d4 = dc * 1024 + threadIdx.x * 4;
  f32x4 acc[3] = {};
  int n0 = a * 192;
  const float* p = x + ((size_t)(l * NTOK + n0)) * DIM + d4;
  u16* q = xb + ((size_t)(l * NTOK + n0)) * DIM + d4;
  for (int nn = 0; nn < 192; nn++) {
    f32x4 v = *(const f32x4*)p;
    u16x4 bv; bv.x = f2bf(v.x); bv.y = f2bf(v.y); bv.z = f2bf(v.z); bv.w = f2bf(v.w);
    *(u16x4*)q = bv;
    int c = (nn >> 3) % 3;
    acc[c] += v;
    p += DIM; q += DIM;
  }
  for (int c = 0; c < 3; c++) {
    f32x4 o = acc[c] * (1.0f / 64.0f);
    *(f32x4*)(gm + ((size_t)(l * 9 + a * 3 + c)) * DIM + d4) = o;
  }
}

// y[l][d] = mean over 9 groups of gm. grid 96
__global__ void k_y(const float* __restrict__ gm, float* __restrict__ y) {
  int bid = blockIdx.x;
  int l = bid >> 2, dc = bid & 3;
  int d4 = dc * 1024 + threadIdx.x * 4;
  f32x4 s = {};
  for (int g = 0; g < 9; g++) s += *(const f32x4*)(gm + ((size_t)(l * 9 + g)) * DIM + d4);
  *(f32x4*)(y + (size_t)l * DIM + d4) = s * (1.0f / 9.0f);
}

// ---------------- Wk -> bf16 ----------------
__global__ void k_conv_wk(const float* __restrict__ wk, u16* __restrict__ wkb) {
  size_t i = (size_t)blockIdx.x * 256 + threadIdx.x;  // float4 index
  f32x4 v = ((const f32x4*)wk)[i];
  u16x4 b; b.x = f2bf(v.x); b.y = f2bf(v.y); b.z = f2bf(v.z); b.w = f2bf(v.w);
  ((u16x4*)wkb)[i] = b;
}

// ---------------- S2 GEMM: rowwise sum of squares of x@Wk^T ----------------
// 128x128 tile, BK=32, 4 waves of 64x64, 16x16x32 bf16 MFMA.
// Register-staged LDS (m92 pattern) — no global_load_lds this round (de-risk).
__global__ __launch_bounds__(256) void k_gemm_s2(const u16* __restrict__ xb,
                                                 const u16* __restrict__ wkb,
                                                 float* __restrict__ s2p) {
  __shared__ __align__(16) u16 As[128 * 32];
  __shared__ __align__(16) u16 Bs[128 * 32];
  int bid = blockIdx.x;
  int mt = bid >> 5, nt = bid & 31;
  int tid = threadIdx.x;
  int wid = tid >> 6, lane = tid & 63;
  int wm = (wid >> 1) * 64, wn = (wid & 1) * 64;
  int lm = lane & 15, qq = lane >> 4;
  f32x4 acc[4][4] = {};
  const u16* gA = xb + (size_t)(mt * 128) * DIM;
  const u16* gB = wkb + (size_t)(nt * 128) * DIM;
  for (int kt = 0; kt < DIM / 32; kt++) {
    int k0 = kt * 32;
    bf16x8 av[2], bv[2];
    for (int j = 0; j < 2; j++) {
      int seg = tid + 256 * j;
      int row = seg >> 2, ko = (seg & 3) * 8;
      av[j] = *(const bf16x8*)(gA + (size_t)row * DIM + k0 + ko);
      bv[j] = *(const bf16x8*)(gB + (size_t)row * DIM + k0 + ko);
    }
    __syncthreads();  // previous iteration's LDS reads complete
    for (int j = 0; j < 2; j++) {
      int seg = tid + 256 * j;
      *(bf16x8*)&As[seg * 8] = av[j];
      *(bf16x8*)&Bs[seg * 8] = bv[j];
    }
    __syncthreads();
    bf16x8 aF[4], bF[4];
    for (int mi = 0; mi < 4; mi++) aF[mi] = *(const bf16x8*)&As[(wm + mi * 16 + lm) * 32 + qq * 8];
    for (int ni = 0; ni < 4; ni++) bF[ni] = *(const bf16x8*)&Bs[(wn + ni * 16 + lm) * 32 + qq * 8];
    for (int mi = 0; mi < 4; mi++)
      for (int ni = 0; ni < 4; ni++)
        acc[mi][ni] = __builtin_amdgcn_mfma_f32_16x16x32_bf16(aF[mi], bF[ni], acc[mi][ni], 0, 0, 0);
  }
  // epilogue: sum of squares over this wave's 64 output cols, per row
  // C/D layout (m89-verified): col=lane&15, row=(lane>>4)*4+reg
  for (int mi = 0; mi < 4; mi++) {
    for (int reg = 0; reg < 4; reg++) {
      float s = 0.f;
      for (int ni = 0; ni < 4; ni++) { float v = acc[mi][ni][reg]; s += v * v; }
      for (int off = 1; off < 16; off <<= 1) s += __shfl_xor(s, off, 64);
      if (lm == 0) {
        int row = mt * 128 + wm + mi * 16 + qq * 4 + reg;
        s2p[(size_t)row * 64 + nt * 2 + (wid & 1)] = s;
      }
    }
  }
}

__global__ void k_s2_reduce(const float* __restrict__ s2p, float* __restrict__ S2) {
  int row = blockIdx.x * 256 + threadIdx.x;  // grid 54
  const f32x4* p = (const f32x4*)(s2p + (size_t)row * 64);
  float s = 0.f;
  for (int i = 0; i < 16; i++) { f32x4 v = p[i]; s += v.x + v.y + v.z + v.w; }
  S2[row] = s;
}

// ---------------- pre[l][r] = b1[r] + W1b@y_l + W1c@tg ----------------
__global__ __launch_bounds__(256) void k_pre(const float* __restrict__ W1, const float* __restrict__ b1,
                                             const float* __restrict__ y, const float* __restrict__ tg,
                                             float* __restrict__ pre) {
  int r = blockIdx.x, t = threadIdx.x;  // grid 1024
  __shared__ float ylds[LAY][256];
  __shared__ float tglds[256];
  __shared__ float red[256];
  float acc[LAY]; for (int l = 0; l < LAY; l++) acc[l] = 0.f;
  float accc = 0.f;
  const float* wb = W1 + (size_t)r * (3 * DIM) + DIM;
  const float* wc = W1 + (size_t)r * (3 * DIM) + 2 * DIM;
  for (int ch = 0; ch < 16; ch++) {
    for (int l = 0; l < LAY; l++) ylds[l][t] = y[(size_t)l * DIM + ch * 256 + t];
    tglds[t] = tg[ch * 256 + t];
    __syncthreads();
    float w1b = wb[ch * 256 + t];
    float w1c = wc[ch * 256 + t];
    for (int l = 0; l < LAY; l++) acc[l] += w1b * ylds[l][t];
    accc += w1c * tglds[t];
    __syncthreads();
  }
  red[t] = accc; __syncthreads();
  for (int o = 128; o; o >>= 1) { if (t < o) red[t] += red[t + o]; __syncthreads(); }
  float csum = red[0]; __syncthreads();
  for (int l = 0; l < LAY; l++) {
    red[t] = acc[l]; __syncthreads();
    for (int o = 128; o; o >>= 1) { if (t < o) red[t] += red[t + o]; __syncthreads(); }
    if (t == 0) pre[l * REDD + r] = b1[r] + red[0] + csum;
    __syncthreads();
  }
}

// ---------------- DSU recurrence: regular launches, u = sigmoid(c) carried ----------------
__global__ void k_dsu_init(float* __restrict__ c_prev, float* __restrict__ u) {
  int i = blockIdx.x * 256 + threadIdx.x;  // grid 16
  c_prev[i] = 0.0f;
  u[i] = 0.5f;  // sigmoid(0)
}

// s = relu(W1a @ u + pre[l]); grid 256 blocks, wave-per-row
__global__ __launch_bounds__(256) void k_dsu1(const float* __restrict__ W1, const float* __restrict__ pre,
                                              const float* __restrict__ u, float* __restrict__ svec,
                                              int l) {
  __shared__ __align__(16) float ulds[DIM];
  int b = blockIdx.x, t = threadIdx.x;
  int wid = t >> 6, lane = t & 63;
  for (int i = 0; i < 16; i++) ulds[i * 256 + t] = u[i * 256 + t];
  __syncthreads();
  int r = b * 4 + wid;
  const float* wrow = W1 + (size_t)r * (3 * DIM);
  float acc = 0.f;
  for (int i = 0; i < 16; i++) {
    int e = i * 256 + lane * 4;
    f32x4 w = *(const f32x4*)(wrow + e);
    f32x4 uv = *(const f32x4*)(&ulds[e]);
    acc += w.x * uv.x + w.y * uv.y + w.z * uv.z + w.w * uv.w;
  }
  for (int off = 32; off; off >>= 1) acc += __shfl_down(acc, off, 64);
  if (lane == 0) {
    float sv = acc + pre[l * REDD + r];
    svec[r] = sv > 0.f ? sv : 0.f;
  }
}

// gates + cell update; grid 1024 blocks, wave handles d = b*4+wid (3 sequential gate dots)
__global__ __launch_bounds__(256) void k_dsu2(
    const float* __restrict__ Wc, const float* __restrict__ Wi, const float* __restrict__ Wf,
    const float* __restrict__ bc_lin, const float* __restrict__ bc,
    const float* __restrict__ bi_lin, const float* __restrict__ bi,
    const float* __restrict__ bf_lin, const float* __restrict__ bf,
    const float* __restrict__ svec, float* __restrict__ c_prev, float* __restrict__ u,
    float* __restrict__ ctx, int l) {
  __shared__ __align__(16) float sl[REDD];
  int b = blockIdx.x, t = threadIdx.x;
  int wid = t >> 6, lane = t & 63;
  for (int i = 0; i < 4; i++) sl[i * 256 + t] = svec[i * 256 + t];
  __syncthreads();
  int d = b * 4 + wid;
  float g3[3];
  for (int gate = 0; gate < 3; gate++) {
    const float* wrow = (gate == 0 ? Wc : (gate == 1 ? Wi : Wf)) + (size_t)d * REDD;
    float acc = 0.f;
    for (int i = 0; i < 4; i++) {
      int k = i * 256 + lane * 4;
      f32x4 w = *(const f32x4*)(wrow + k);
      f32x4 sv = *(const f32x4*)(&sl[k]);
      acc += w.x * sv.x + w.y * sv.y + w.z * sv.z + w.w * sv.w;
    }
    for (int off = 32; off; off >>= 1) acc += __shfl_down(acc, off, 64);
    g3[gate] = acc;
  }
  if (lane == 0) {
    float ct = tanhf(g3[0] + bc_lin[d] + bc[d]);
    float iv = sigm(g3[1] + bi_lin[d] + bi[d]);
    float fv = sigm(g3[2] + bf_lin[d] + bf[d]);
    float c = fv * c_prev[d] + iv * ct;
    c_prev[d] = c;
    u[d] = sigm(c);
    ctx[(size_t)l * DIM + d] = c;
  }
}

// ---------------- q_pre[l][e] = ctx[l] . Wq[e,:]  (grid 1024, wave-per-e) ----------------
__global__ __launch_bounds__(256) void k_qpre(const float* __restrict__ ctx, const float* __restrict__ Wq,
                                              float* __restrict__ qpre) {
  __shared__ __align__(16) float clds[LAY][512];  // 48KB
  int b = blockIdx.x, t = threadIdx.x;
  int wid = t >> 6, lane = t & 63;
  int e = b * 4 + wid;
  const float* wrow = Wq + (size_t)e * DIM;
  float acc[LAY]; for (int l = 0; l < LAY; l++) acc[l] = 0.f;
  for (int ch = 0; ch < 8; ch++) {
    for (int i = 0; i < 48; i++) {
      int idx = i * 256 + t;
      int l = idx >> 9, dd = idx & 511;
      clds[l][dd] = ctx[(size_t)l * DIM + ch * 512 + dd];
    }
    __syncthreads();
    for (int i = 0; i < 2; i++) {
      int dd = i * 256 + lane * 4;
      f32x4 w = *(const f32x4*)(wrow + ch * 512 + dd);
      for (int l = 0; l < LAY; l++) {
        f32x4 c = *(const f32x4*)(&clds[l][dd]);
        acc[l] += w.x * c.x + w.y * c.y + w.z * c.z + w.w * c.w;
      }
    }
    __syncthreads();
  }
  for (int l = 0; l < LAY; l++) {
    float s = acc[l];
    for (int off = 32; off; off >>= 1) s += __shfl_down(s, off, 64);
    if (lane == 0) qpre[(size_t)l * DIM + e] = s;
  }
}

// ---------------- LN(q) -> h = g*q, A = sum(h), B = sum(b*q) ----------------
__global__ void k_qln(const float* __restrict__ qpre, const float* __restrict__ g, const float* __restrict__ bb,
                      float* __restrict__ h, float* __restrict__ A, float* __restrict__ Bv) {
  int l = blockIdx.x, t = threadIdx.x;  // grid 24
  __shared__ float red[256];
  float x[16]; float s = 0.f;
  for (int i = 0; i < 16; i++) { x[i] = qpre[(size_t)l * DIM + i * 256 + t]; s += x[i]; }
  red[t] = s; __syncthreads();
  for (int o = 128; o; o >>= 1) { if (t < o) red[t] += red[t + o]; __syncthreads(); }
  float mean = red[0] / DIM; __syncthreads();
  float qs = 0.f;
  for (int i = 0; i < 16; i++) { float dd = x[i] - mean; qs += dd * dd; }
  red[t] = qs; __syncthreads();
  for (int o = 128; o; o >>= 1) { if (t < o) red[t] += red[t + o]; __syncthreads(); }
  float var = red[0] / DIM;
  float rinv = 1.0f / sqrtf(var + 1e-5f);
  float sa = 0.f, sb = 0.f;
  for (int i = 0; i < 16; i++) {
    int d = i * 256 + t;
    float gv = g[d], bv = bb[d];
    float qv = (x[i] - mean) * rinv * gv + bv;
    float hv = gv * qv;
    h[(size_t)l * DIM + d] = hv;
    sa += hv; sb += bv * qv;
  }
  __syncthreads();
  red[t] = sa; __syncthreads();
  for (int o = 128; o; o >>= 1) { if (t < o) red[t] += red[t + o]; __syncthreads(); }
  if (t == 0) A[l] = red[0];
  __syncthreads();
  red[t] = sb; __syncthreads();
  for (int o = 128; o; o >>= 1) { if (t < o) red[t] += red[t + o]; __syncthreads(); }
  if (t == 0) Bv[l] = red[0];
}

// ---------------- v_l[e] = sum_d Wk[d,e] h_l[d];  wmu[e] = sum_d Wk[d,e]/D ----------------
__global__ __launch_bounds__(256) void k_v(const float* __restrict__ Wk, const float* __restrict__ h,
                                           float* __restrict__ v, float* __restrict__ wmu) {
  int eb = blockIdx.x & 15, db = blockIdx.x >> 4;  // grid 256
  int t = threadIdx.x;
  __shared__ float hl[LAY][256];
  for (int l = 0; l < LAY; l++) hl[l][t] = h[(size_t)l * DIM + db * 256 + t];
  __syncthreads();
  int e = eb * 256 + t;
  float acc[LAY]; for (int l = 0; l < LAY; l++) acc[l] = 0.f;
  float am = 0.f;
  for (int dd = 0; dd < 256; dd++) {
    float w = Wk[(size_t)(db * 256 + dd) * DIM + e];
    am += w;
    for (int l = 0; l < LAY; l++) acc[l] += w * hl[l][dd];
  }
  for (int l = 0; l < LAY; l++) atomicAdd(&v[(size_t)l * DIM + e], acc[l]);
  atomicAdd(&wmu[e], am * (1.0f / DIM));
}

// ---------------- per-row dot = x.v_l, mu = x.w_mu ----------------
__global__ __launch_bounds__(256) void k_dotmu(const float* __restrict__ x, const float* __restrict__ v,
                                               const float* __restrict__ wmu, float* __restrict__ dotv,
                                               float* __restrict__ muv) {
  __shared__ __align__(16) float vl[DIM];
  __shared__ __align__(16) float wm[DIM];
  int bid = blockIdx.x;  // grid 24*144
  int l = bid / 144, n4 = bid % 144;
  int t = threadIdx.x, wid = t >> 6, lane = t & 63;
  for (int i = 0; i < 16; i++) {
    int idx = i * 256 + t;
    vl[idx] = v[(size_t)l * DIM + idx];
    wm[idx] = wmu[idx];
  }
  __syncthreads();
  int n = n4 * 4 + wid;
  const float* row = x + (size_t)(l * NTOK + n) * DIM;
  float ad = 0.f, am = 0.f;
  for (int i = 0; i < 16; i++) {
    int e = i * 256 + lane * 4;
    f32x4 xv = *(const f32x4*)(row + e);
    f32x4 vv = *(const f32x4*)(&vl[e]);
    f32x4 wv = *(const f32x4*)(&wm[e]);
    ad += xv.x * vv.x + xv.y * vv.y + xv.z * vv.z + xv.w * vv.w;
    am += xv.x * wv.x + xv.y * wv.y + xv.z * wv.z + xv.w * wv.w;
  }
  for (int off = 32; off; off >>= 1) { ad += __shfl_down(ad, off, 64); am += __shfl_down(am, off, 64); }
  if (lane == 0) { dotv[l * NTOK + n] = ad; muv[l * NTOK + n] = am; }
}

// ---------------- scores, conf, per-layer top-32 ----------------
__global__ void k_scores(const float* __restrict__ dotv, const float* __restrict__ muv,
                         const float* __restrict__ S2, const float* __restrict__ A, const float* __restrict__ Bv,
                         int* __restrict__ topidx, float* __restrict__ conf) {
  int l = blockIdx.x, t = threadIdx.x;  // grid 24
  __shared__ float raw[NTOK];
  __shared__ float rv[256]; __shared__ int ri[256];
  float Al = A[l], Bl = Bv[l];
  for (int j = t; j < NTOK; j += 256) {
    float dv = dotv[l * NTOK + j], mv = muv[l * NTOK + j];
    float var = S2[l * NTOK + j] * (1.0f / DIM) - mv * mv;
    float sd = sqrtf(var + 1e-5f);
    raw[j] = (dv - mv * Al) / sd + Bl;
  }
  __syncthreads();
  float s = 0.f;
  for (int j = t; j < NTOK; j += 256) s += raw[j];
  rv[t] = s; __syncthreads();
  for (int o = 128; o; o >>= 1) { if (t < o) rv[t] += rv[t + o]; __syncthreads(); }
  float mean = rv[0] / NTOK; __syncthreads();
  float qsum = 0.f;
  for (int j = t; j < NTOK; j += 256) { float d = raw[j] - mean; qsum += d * d; }
  rv[t] = qsum; __syncthreads();
  for (int o = 128; o; o >>= 1) { if (t < o) rv[t] += rv[t + o]; __syncthreads(); }
  float sdn = sqrtf(rv[0] / NTOK) + 1e-6f; __syncthreads();
  // iterative top-32 on raw (order invariant under the affine normalization; ties -> lowest idx)
  for (int k = 0; k < 32; k++) {
    float bvv = -INFINITY; int bii = NTOK;
    for (int j = t; j < NTOK; j += 256) {
      float vv = raw[j];
      if (vv > bvv || (vv == bvv && j < bii)) { bvv = vv; bii = j; }
    }
    rv[t] = bvv; ri[t] = bii; __syncthreads();
    for (int o = 128; o; o >>= 1) {
      if (t < o) {
        if (rv[t + o] > rv[t] || (rv[t + o] == rv[t] && ri[t + o] < ri[t])) { rv[t] = rv[t + o]; ri[t] = ri[t + o]; }
      }
      __syncthreads();
    }
    if (t == 0) {
      topidx[l * 32 + k] = ri[0];
      if (k == 0) conf[l] = (rv[0] - mean) / sdn;
      raw[ri[0]] = -INFINITY;
    }
    __syncthreads();
  }
}

// ---------------- serial selection logic + alpha softmax ----------------
__global__ void k_select(const float* __restrict__ conf, const int* __restrict__ topidx,
                         const float* __restrict__ logits,
                         int* __restrict__ src, float* __restrict__ alpha) {
  if (threadIdx.x != 0 || blockIdx.x != 0) return;
  float cf[LAY]; for (int l = 0; l < LAY; l++) cf[l] = conf[l];
  bool actt[LAY]; int Mt = 0;
  for (int l = 0; l < LAY; l++) { actt[l] = (l != FOCUSL) && (cf[l] > 3.0f); if (actt[l]) Mt++; }
  bool act[LAY]; int pos[LAY]; int M;
  if (Mt < 8) {
    float cnf[LAY];
    for (int l = 0; l < LAY; l++) cnf[l] = (l == FOCUSL) ? -INFINITY : cf[l];
    bool used[LAY] = {};
    for (int l = 0; l < LAY; l++) { act[l] = false; pos[l] = LAY; }
    for (int j = 0; j < 8; j++) {
      float bv = -INFINITY; int bidx = -1;
      for (int l = 0; l < LAY; l++) if (!used[l] && cnf[l] > bv) { bv = cnf[l]; bidx = l; }
      used[bidx] = true; act[bidx] = true; pos[bidx] = j;
    }
    M = 8;
  } else {
    int c = 0;
    for (int l = 0; l < LAY; l++) { act[l] = actt[l]; if (actt[l]) { pos[l] = c; c++; } else pos[l] = -1; }
    M = Mt;
  }
  int base = 32 / M, rem = 32 - base * M;
  int kk[LAY]; int cum[LAY]; int run = 0;
  for (int l = 0; l < LAY; l++) {
    int k = act[l] ? (base + ((pos[l] < rem) ? 1 : 0)) : 0;
    kk[l] = k; run += k; cum[l] = run;
  }
  for (int tt = 0; tt < 32; tt++) src[tt] = FOCUSL * NTOK + topidx[FOCUSL * 32 + tt];
  for (int tt = 0; tt < 32; tt++) {
    int li = 0;
    while (cum[li] <= tt) li++;
    int r = tt - (cum[li] - kk[li]);
    src[32 + tt] = li * NTOK + topidx[li * 32 + r];
  }
  float mx = -INFINITY;
  for (int l = 0; l < LAY; l++) if (l != FOCUSL && logits[l] > mx) mx = logits[l];
  float ssum = 0.f; float av[LAY];
  for (int l = 0; l < LAY; l++) { av[l] = (l == FOCUSL) ? 0.0f : expf(logits[l] - mx); ssum += av[l]; }
  for (int l = 0; l < LAY; l++) alpha[l] = av[l] / ssum;
}

// ---------------- gather evidence rows ----------------
__global__ void k_gather(const float* __restrict__ x, const int* __restrict__ src, float* __restrict__ out) {
  int b = blockIdx.x, t = threadIdx.x;  // grid 64
  const float* row = x + (size_t)src[b] * DIM;
  float* o = out + (size_t)b * DIM;
  for (int i = 0; i < 4; i++) {
    int e = (i * 256 + t) * 4;
    *(f32x4*)(o + e) = *(const f32x4*)(row + e);
  }
}

// ---------------- group outputs ----------------
__global__ void k_groups(const float* __restrict__ gm, const float* __restrict__ alpha,
                         const float* __restrict__ scale, float* __restrict__ out) {
  int g = blockIdx.x, t = threadIdx.x;  // grid 9
  float sc = scale[0];
  __shared__ float al[LAY];
  if (t < LAY) al[t] = alpha[t];
  __syncthreads();
  for (int i = 0; i < 4; i++) {
    int d = (i * 256 + t) * 4;
    f32x4 mix = {};
    for (int l = 0; l < LAY; l++) {
      f32x4 gv = *(const f32x4*)(gm + ((size_t)(l * 9 + g)) * DIM + d);
      mix += gv * al[l];
    }
    f32x4 anc = *(const f32x4*)(gm + ((size_t)(FOCUSL * 9 + g)) * DIM + d);
    f32x4 o = anc + (mix - anc) * sc;
    *(f32x4*)(out + (size_t)(64 + g) * DIM + d) = o;
  }
}

extern "C" void kernel_launch(void* const* d_in, const int* in_sizes, int n_in,
                              void* d_out, int out_size, void* d_ws, size_t ws_size,
                              hipStream_t stream) {
  const float* tf     = (const float*)d_in[0];
  const float* x      = (const float*)d_in[1];
  const float* W1     = (const float*)d_in[2];
  const float* b1     = (const float*)d_in[3];
  const float* Wc     = (const float*)d_in[4];
  const float* bc_lin = (const float*)d_in[5];
  const float* bc     = (const float*)d_in[6];
  const float* Wi     = (const float*)d_in[7];
  const float* bi_lin = (const float*)d_in[8];
  const float* bi     = (const float*)d_in[9];
  const float* Wf     = (const float*)d_in[10];
  const float* bf_lin = (const float*)d_in[11];
  const float* bf     = (const float*)d_in[12];
  const float* Wq     = (const float*)d_in[13];
  const float* Wk     = (const float*)d_in[14];
  const float* ln_g   = (const float*)d_in[15];
  const float* ln_b   = (const float*)d_in[16];
  const float* logits = (const float*)d_in[17];
  const float* scale  = (const float*)d_in[18];
  float* out = (float*)d_out;

  char* w = (char*)d_ws;
  size_t off = 0;
  auto alloc = [&](size_t bytes) -> void* {
    void* p = w + off;
    off += (bytes + 255) & ~(size_t)255;
    return p;
  };
  // atomic-accumulated buffers first (one memset)
  float* v    = (float*)alloc((size_t)LAY * DIM * 4);
  float* wmu  = (float*)alloc((size_t)DIM * 4);
  size_t zero_bytes = off;
  u16* xb     = (u16*)alloc((size_t)LAY * NTOK * DIM * 2);
  u16* wkb    = (u16*)alloc((size_t)DIM * DIM * 2);
  float* gm   = (float*)alloc((size_t)LAY * 9 * DIM * 4);
  float* y    = (float*)alloc((size_t)LAY * DIM * 4);
  float* tmean= (float*)alloc((size_t)DIM * 4);
  float* tg   = (float*)alloc((size_t)DIM * 4);
  float* pre  = (float*)alloc((size_t)LAY * REDD * 4);
  float* svec = (float*)alloc((size_t)REDD * 4);
  float* cprev= (float*)alloc((size_t)DIM * 4);
  float* uvec = (float*)alloc((size_t)DIM * 4);
  float* ctx  = (float*)alloc((size_t)LAY * DIM * 4);
  float* qpre = (float*)alloc((size_t)LAY * DIM * 4);
  float* h    = (float*)alloc((size_t)LAY * DIM * 4);
  float* A    = (float*)alloc((size_t)LAY * 4);
  float* Bv   = (float*)alloc((size_t)LAY * 4);
  float* s2p  = (float*)alloc((size_t)LAY * NTOK * 64 * 4);
  float* S2   = (float*)alloc((size_t)LAY * NTOK * 4);
  float* dotv = (float*)alloc((size_t)LAY * NTOK * 4);
  float* muv  = (float*)alloc((size_t)LAY * NTOK * 4);
  int* topidx = (int*)alloc((size_t)LAY * 32 * 4);
  float* conf = (float*)alloc((size_t)LAY * 4);
  int* src    = (int*)alloc(64 * 4);
  float* alph = (float*)alloc((size_t)LAY * 4);
  (void)in_sizes; (void)n_in; (void)out_size; (void)ws_size;

  hipMemsetAsync(d_ws, 0, zero_bytes, stream);
  k_text_colmean<<<16, 256, 0, stream>>>(tf, tmean);
  k_text_ln<<<1, 256, 0, stream>>>(tmean, tg);
  k_pass_a<<<288, 256, 0, stream>>>(x, xb, gm);
  k_y<<<96, 256, 0, stream>>>(gm, y);
  k_conv_wk<<<16384, 256, 0, stream>>>(Wk, wkb);
  k_gemm_s2<<<108 * 32, 256, 0, stream>>>(xb, wkb, s2p);
  k_s2_reduce<<<54, 256, 0, stream>>>(s2p, S2);
  k_pre<<<1024, 256, 0, stream>>>(W1, b1, y, tg, pre);
  k_dsu_init<<<16, 256, 0, stream>>>(cprev, uvec);
  for (int l = 0; l < LAY; l++) {
    k_dsu1<<<256, 256, 0, stream>>>(W1, pre, uvec, svec, l);
    k_dsu2<<<1024, 256, 0, stream>>>(Wc, Wi, Wf, bc_lin, bc, bi_lin, bi, bf_lin, bf,
                                     svec, cprev, uvec, ctx, l);
  }
  k_qpre<<<1024, 256, 0, stream>>>(ctx, Wq, qpre);
  k_qln<<<24, 256, 0, stream>>>(qpre, ln_g, ln_b, h, A, Bv);
  k_v<<<256, 256, 0, stream>>>(Wk, h, v, wmu);
  k_dotmu<<<24 * 144, 256, 0, stream>>>(x, v, wmu, dotv, muv);
  k_scores<<<24, 256, 0, stream>>>(dotv, muv, S2, A, Bv, topidx, conf);
  k_select<<<1, 64, 0, stream>>>(conf, topidx, logits, src, alph);
  k_gather<<<64, 256, 0, stream>>>(x, src, out);
  k_groups<<<9, 256, 0, stream>>>(gm, alph, scale, out);
}

// Round 3
// 2055.101 us; speedup vs baseline: 1.0309x; 1.0309x over previous
//
#include <hip/hip_runtime.h>
#include <stdint.h>
#include <math.h>

#define LAY 24
#define NTOK 576
#define DIM 4096
#define TTXT 128
#define REDD 1024
#define FOCUSL 22

typedef unsigned int u32;
typedef unsigned short u16;
typedef float f32x4 __attribute__((ext_vector_type(4)));
typedef short bf16x8 __attribute__((ext_vector_type(8)));
typedef u16 u16x4 __attribute__((ext_vector_type(4)));

__device__ __forceinline__ u16 f2bf(float f) {
  u32 u = __builtin_bit_cast(u32, f);
  u32 r = u + 0x7fffu + ((u >> 16) & 1u);
  return (u16)(r >> 16);
}
__device__ __forceinline__ float sigm(float x) { return 1.0f / (1.0f + expf(-x)); }

#define GLOBAL_AS __attribute__((address_space(1)))
#define LDS_AS __attribute__((address_space(3)))
__device__ __forceinline__ void gld_lds16(const void* g, void* l) {
  __builtin_amdgcn_global_load_lds((const GLOBAL_AS u32*)g, (LDS_AS u32*)l, 16, 0, 0);
}

// ---------------- text conditioning ----------------
__global__ void k_text_colmean(const float* __restrict__ tf, float* __restrict__ tmean) {
  int c = blockIdx.x * 256 + threadIdx.x;
  float s = 0.f;
  for (int r = 0; r < TTXT; r++) s += tf[(size_t)r * DIM + c];
  tmean[c] = s * (1.0f / TTXT);
}

__global__ void k_text_ln(const float* __restrict__ tmean, float* __restrict__ tg) {
  __shared__ float red[256];
  int t = threadIdx.x;
  float x[16]; float s = 0.f;
  for (int i = 0; i < 16; i++) { x[i] = tmean[i * 256 + t]; s += x[i]; }
  red[t] = s; __syncthreads();
  for (int o = 128; o; o >>= 1) { if (t < o) red[t] += red[t + o]; __syncthreads(); }
  float mean = red[0] / DIM; __syncthreads();
  float q = 0.f;
  for (int i = 0; i < 16; i++) { float d = x[i] - mean; q += d * d; }
  red[t] = q; __syncthreads();
  for (int o = 128; o; o >>= 1) { if (t < o) red[t] += red[t + o]; __syncthreads(); }
  float var = red[0] / DIM;
  float rinv = 1.0f / sqrtf(var + 1e-5f);
  for (int i = 0; i < 16; i++) tg[i * 256 + t] = (x[i] - mean) * rinv;
}

// ---------------- pass A: group means + bf16 conversion ----------------
// grid = 24 (l) * 8 (dc of 512) * 3 (a of 192 rows) = 576 blocks, 128 thr
__global__ void k_pass_a(const float* __restrict__ x, u16* __restrict__ xb,
                         float* __restrict__ gm) {
  int bid = blockIdx.x;
  int a = bid % 3, dc = (bid / 3) & 7, l = bid / 24;
  int d4 = dc * 512 + threadIdx.x * 4;
  f32x4 acc[3] = {};
  int n0 = a * 192;
  const float* p = x + ((size_t)(l * NTOK + n0)) * DIM + d4;
  u16* q = xb + ((size_t)(l * NTOK + n0)) * DIM + d4;
  for (int nn = 0; nn < 192; nn++) {
    f32x4 v = *(const f32x4*)p;
    u16x4 bv; bv.x = f2bf(v.x); bv.y = f2bf(v.y); bv.z = f2bf(v.z); bv.w = f2bf(v.w);
    *(u16x4*)q = bv;
    int c = (nn >> 3) % 3;
    acc[c] += v;
    p += DIM; q += DIM;
  }
  for (int c = 0; c < 3; c++) {
    f32x4 o = acc[c] * (1.0f / 64.0f);
    *(f32x4*)(gm + ((size_t)(l * 9 + a * 3 + c)) * DIM + d4) = o;
  }
}

// y[l][d] = mean over 9 groups of gm. grid 96
__global__ void k_y(const float* __restrict__ gm, float* __restrict__ y) {
  int bid = blockIdx.x;
  int l = bid >> 2, dc = bid & 3;
  int d4 = dc * 1024 + threadIdx.x * 4;
  f32x4 s = {};
  for (int g = 0; g < 9; g++) s += *(const f32x4*)(gm + ((size_t)(l * 9 + g)) * DIM + d4);
  *(f32x4*)(y + (size_t)l * DIM + d4) = s * (1.0f / 9.0f);
}

// ---------------- Wk -> bf16 ----------------
__global__ void k_conv_wk(const float* __restrict__ wk, u16* __restrict__ wkb) {
  size_t i = (size_t)blockIdx.x * 256 + threadIdx.x;  // float4 index
  f32x4 v = ((const f32x4*)wk)[i];
  u16x4 b; b.x = f2bf(v.x); b.y = f2bf(v.y); b.z = f2bf(v.z); b.w = f2bf(v.w);
  ((u16x4*)wkb)[i] = b;
}

// ---------------- S2 GEMM: rowwise sum of squares of x@Wk^T ----------------
// 128x128 tile, BK=32, 4 waves of 64x64, 16x16x32 bf16 MFMA.
// m97 staging: barrier -> global_load_lds(16B) -> barrier -> ds_read+mfma.
__global__ __launch_bounds__(256) void k_gemm_s2(const u16* __restrict__ xb,
                                                 const u16* __restrict__ wkb,
                                                 float* __restrict__ s2p) {
  __shared__ __align__(16) u16 As[128 * 32];
  __shared__ __align__(16) u16 Bs[128 * 32];
  int bid = blockIdx.x;
  int mt = bid >> 5, nt = bid & 31;
  int tid = threadIdx.x;
  int wid = tid >> 6, lane = tid & 63;
  int wm = (wid >> 1) * 64, wn = (wid & 1) * 64;
  int lm = lane & 15, qq = lane >> 4;
  f32x4 acc[4][4] = {};
  const u16* gA = xb + (size_t)(mt * 128) * DIM;
  const u16* gB = wkb + (size_t)(nt * 128) * DIM;
  for (int kt = 0; kt < DIM / 32; kt++) {
    int k0 = kt * 32;
    __syncthreads();  // all waves done reading previous tile BEFORE DMA overwrites LDS
    for (int j = 0; j < 2; j++) {
      int seg = tid + 256 * j;
      int row = seg >> 2, ko = (seg & 3) * 8;
      gld_lds16(gA + (size_t)row * DIM + k0 + ko, &As[seg * 8]);
      gld_lds16(gB + (size_t)row * DIM + k0 + ko, &Bs[seg * 8]);
    }
    __syncthreads();  // compiler drains vmcnt(0) before barrier -> staged data visible
    bf16x8 aF[4], bF[4];
    for (int mi = 0; mi < 4; mi++) aF[mi] = *(const bf16x8*)&As[(wm + mi * 16 + lm) * 32 + qq * 8];
    for (int ni = 0; ni < 4; ni++) bF[ni] = *(const bf16x8*)&Bs[(wn + ni * 16 + lm) * 32 + qq * 8];
    for (int mi = 0; mi < 4; mi++)
      for (int ni = 0; ni < 4; ni++)
        acc[mi][ni] = __builtin_amdgcn_mfma_f32_16x16x32_bf16(aF[mi], bF[ni], acc[mi][ni], 0, 0, 0);
  }
  // epilogue: sum of squares over this wave's 64 output cols, per row
  // C/D layout (m89-verified): col=lane&15, row=(lane>>4)*4+reg
  for (int mi = 0; mi < 4; mi++) {
    for (int reg = 0; reg < 4; reg++) {
      float s = 0.f;
      for (int ni = 0; ni < 4; ni++) { float v = acc[mi][ni][reg]; s += v * v; }
      for (int off = 1; off < 16; off <<= 1) s += __shfl_xor(s, off, 64);
      if (lm == 0) {
        int row = mt * 128 + wm + mi * 16 + qq * 4 + reg;
        s2p[(size_t)row * 64 + nt * 2 + (wid & 1)] = s;
      }
    }
  }
}

__global__ void k_s2_reduce(const float* __restrict__ s2p, float* __restrict__ S2) {
  int row = blockIdx.x * 256 + threadIdx.x;  // grid 54
  const f32x4* p = (const f32x4*)(s2p + (size_t)row * 64);
  float s = 0.f;
  for (int i = 0; i < 16; i++) { f32x4 v = p[i]; s += v.x + v.y + v.z + v.w; }
  S2[row] = s;
}

// ---------------- pre[l][r] = b1[r] + W1b@y_l + W1c@tg ----------------
__global__ __launch_bounds__(256) void k_pre(const float* __restrict__ W1, const float* __restrict__ b1,
                                             const float* __restrict__ y, const float* __restrict__ tg,
                                             float* __restrict__ pre) {
  int r = blockIdx.x, t = threadIdx.x;  // grid 1024
  __shared__ float ylds[LAY][256];
  __shared__ float tglds[256];
  __shared__ float red[256];
  float acc[LAY]; for (int l = 0; l < LAY; l++) acc[l] = 0.f;
  float accc = 0.f;
  const float* wb = W1 + (size_t)r * (3 * DIM) + DIM;
  const float* wc = W1 + (size_t)r * (3 * DIM) + 2 * DIM;
  for (int ch = 0; ch < 16; ch++) {
    for (int l = 0; l < LAY; l++) ylds[l][t] = y[(size_t)l * DIM + ch * 256 + t];
    tglds[t] = tg[ch * 256 + t];
    __syncthreads();
    float w1b = wb[ch * 256 + t];
    float w1c = wc[ch * 256 + t];
    for (int l = 0; l < LAY; l++) acc[l] += w1b * ylds[l][t];
    accc += w1c * tglds[t];
    __syncthreads();
  }
  red[t] = accc; __syncthreads();
  for (int o = 128; o; o >>= 1) { if (t < o) red[t] += red[t + o]; __syncthreads(); }
  float csum = red[0]; __syncthreads();
  for (int l = 0; l < LAY; l++) {
    red[t] = acc[l]; __syncthreads();
    for (int o = 128; o; o >>= 1) { if (t < o) red[t] += red[t + o]; __syncthreads(); }
    if (t == 0) pre[l * REDD + r] = b1[r] + red[0] + csum;
    __syncthreads();
  }
}

// ---------------- DSU recurrence: regular launches, u = sigmoid(c) carried ----------------
__global__ void k_dsu_init(float* __restrict__ c_prev, float* __restrict__ u) {
  int i = blockIdx.x * 256 + threadIdx.x;  // grid 16
  c_prev[i] = 0.0f;
  u[i] = 0.5f;  // sigmoid(0)
}

// s = relu(W1a @ u + pre[l]); grid 256 blocks, wave-per-row
__global__ __launch_bounds__(256) void k_dsu1(const float* __restrict__ W1, const float* __restrict__ pre,
                                              const float* __restrict__ u, float* __restrict__ svec,
                                              int l) {
  __shared__ __align__(16) float ulds[DIM];
  int b = blockIdx.x, t = threadIdx.x;
  int wid = t >> 6, lane = t & 63;
  for (int i = 0; i < 16; i++) ulds[i * 256 + t] = u[i * 256 + t];
  __syncthreads();
  int r = b * 4 + wid;
  const float* wrow = W1 + (size_t)r * (3 * DIM);
  float acc = 0.f;
  for (int i = 0; i < 16; i++) {
    int e = i * 256 + lane * 4;
    f32x4 w = *(const f32x4*)(wrow + e);
    f32x4 uv = *(const f32x4*)(&ulds[e]);
    acc += w.x * uv.x + w.y * uv.y + w.z * uv.z + w.w * uv.w;
  }
  for (int off = 32; off; off >>= 1) acc += __shfl_down(acc, off, 64);
  if (lane == 0) {
    float sv = acc + pre[l * REDD + r];
    svec[r] = sv > 0.f ? sv : 0.f;
  }
}

// gates + cell update; grid 1024 blocks, wave handles d = b*4+wid (3 sequential gate dots)
__global__ __launch_bounds__(256) void k_dsu2(
    const float* __restrict__ Wc, const float* __restrict__ Wi, const float* __restrict__ Wf,
    const float* __restrict__ bc_lin, const float* __restrict__ bc,
    const float* __restrict__ bi_lin, const float* __restrict__ bi,
    const float* __restrict__ bf_lin, const float* __restrict__ bf,
    const float* __restrict__ svec, float* __restrict__ c_prev, float* __restrict__ u,
    float* __restrict__ ctx, int l) {
  __shared__ __align__(16) float sl[REDD];
  int b = blockIdx.x, t = threadIdx.x;
  int wid = t >> 6, lane = t & 63;
  for (int i = 0; i < 4; i++) sl[i * 256 + t] = svec[i * 256 + t];
  __syncthreads();
  int d = b * 4 + wid;
  float g3[3];
  for (int gate = 0; gate < 3; gate++) {
    const float* wrow = (gate == 0 ? Wc : (gate == 1 ? Wi : Wf)) + (size_t)d * REDD;
    float acc = 0.f;
    for (int i = 0; i < 4; i++) {
      int k = i * 256 + lane * 4;
      f32x4 w = *(const f32x4*)(wrow + k);
      f32x4 sv = *(const f32x4*)(&sl[k]);
      acc += w.x * sv.x + w.y * sv.y + w.z * sv.z + w.w * sv.w;
    }
    for (int off = 32; off; off >>= 1) acc += __shfl_down(acc, off, 64);
    g3[gate] = acc;
  }
  if (lane == 0) {
    float ct = tanhf(g3[0] + bc_lin[d] + bc[d]);
    float iv = sigm(g3[1] + bi_lin[d] + bi[d]);
    float fv = sigm(g3[2] + bf_lin[d] + bf[d]);
    float c = fv * c_prev[d] + iv * ct;
    c_prev[d] = c;
    u[d] = sigm(c);
    ctx[(size_t)l * DIM + d] = c;
  }
}

// ---------------- q_pre[l][e] = ctx[l] . Wq[e,:]  (grid 1024, wave-per-e) ----------------
__global__ __launch_bounds__(256) void k_qpre(const float* __restrict__ ctx, const float* __restrict__ Wq,
                                              float* __restrict__ qpre) {
  __shared__ __align__(16) float clds[LAY][512];  // 48KB
  int b = blockIdx.x, t = threadIdx.x;
  int wid = t >> 6, lane = t & 63;
  int e = b * 4 + wid;
  const float* wrow = Wq + (size_t)e * DIM;
  float acc[LAY]; for (int l = 0; l < LAY; l++) acc[l] = 0.f;
  for (int ch = 0; ch < 8; ch++) {
    for (int i = 0; i < 48; i++) {
      int idx = i * 256 + t;
      int l = idx >> 9, dd = idx & 511;
      clds[l][dd] = ctx[(size_t)l * DIM + ch * 512 + dd];
    }
    __syncthreads();
    for (int i = 0; i < 2; i++) {
      int dd = i * 256 + lane * 4;
      f32x4 w = *(const f32x4*)(wrow + ch * 512 + dd);
      for (int l = 0; l < LAY; l++) {
        f32x4 c = *(const f32x4*)(&clds[l][dd]);
        acc[l] += w.x * c.x + w.y * c.y + w.z * c.z + w.w * c.w;
      }
    }
    __syncthreads();
  }
  for (int l = 0; l < LAY; l++) {
    float s = acc[l];
    for (int off = 32; off; off >>= 1) s += __shfl_down(s, off, 64);
    if (lane == 0) qpre[(size_t)l * DIM + e] = s;
  }
}

// ---------------- LN(q) -> h = g*q, A = sum(h), B = sum(b*q) ----------------
__global__ void k_qln(const float* __restrict__ qpre, const float* __restrict__ g, const float* __restrict__ bb,
                      float* __restrict__ h, float* __restrict__ A, float* __restrict__ Bv) {
  int l = blockIdx.x, t = threadIdx.x;  // grid 24
  __shared__ float red[256];
  float x[16]; float s = 0.f;
  for (int i = 0; i < 16; i++) { x[i] = qpre[(size_t)l * DIM + i * 256 + t]; s += x[i]; }
  red[t] = s; __syncthreads();
  for (int o = 128; o; o >>= 1) { if (t < o) red[t] += red[t + o]; __syncthreads(); }
  float mean = red[0] / DIM; __syncthreads();
  float qs = 0.f;
  for (int i = 0; i < 16; i++) { float dd = x[i] - mean; qs += dd * dd; }
  red[t] = qs; __syncthreads();
  for (int o = 128; o; o >>= 1) { if (t < o) red[t] += red[t + o]; __syncthreads(); }
  float var = red[0] / DIM;
  float rinv = 1.0f / sqrtf(var + 1e-5f);
  float sa = 0.f, sb = 0.f;
  for (int i = 0; i < 16; i++) {
    int d = i * 256 + t;
    float gv = g[d], bv = bb[d];
    float qv = (x[i] - mean) * rinv * gv + bv;
    float hv = gv * qv;
    h[(size_t)l * DIM + d] = hv;
    sa += hv; sb += bv * qv;
  }
  __syncthreads();
  red[t] = sa; __syncthreads();
  for (int o = 128; o; o >>= 1) { if (t < o) red[t] += red[t + o]; __syncthreads(); }
  if (t == 0) A[l] = red[0];
  __syncthreads();
  red[t] = sb; __syncthreads();
  for (int o = 128; o; o >>= 1) { if (t < o) red[t] += red[t + o]; __syncthreads(); }
  if (t == 0) Bv[l] = red[0];
}

// ---------------- v_l[e] = sum_d Wk[d,e] h_l[d];  wmu[e] = sum_d Wk[d,e]/D ----------------
__global__ __launch_bounds__(256) void k_v(const float* __restrict__ Wk, const float* __restrict__ h,
                                           float* __restrict__ v, float* __restrict__ wmu) {
  int eb = blockIdx.x & 15, db = blockIdx.x >> 4;  // grid 256
  int t = threadIdx.x;
  __shared__ float hl[LAY][256];
  for (int l = 0; l < LAY; l++) hl[l][t] = h[(size_t)l * DIM + db * 256 + t];
  __syncthreads();
  int e = eb * 256 + t;
  float acc[LAY]; for (int l = 0; l < LAY; l++) acc[l] = 0.f;
  float am = 0.f;
  for (int dd = 0; dd < 256; dd++) {
    float w = Wk[(size_t)(db * 256 + dd) * DIM + e];
    am += w;
    for (int l = 0; l < LAY; l++) acc[l] += w * hl[l][dd];
  }
  for (int l = 0; l < LAY; l++) atomicAdd(&v[(size_t)l * DIM + e], acc[l]);
  atomicAdd(&wmu[e], am * (1.0f / DIM));
}

// ---------------- per-row dot = x.v_l, mu = x.w_mu ----------------
__global__ __launch_bounds__(256) void k_dotmu(const float* __restrict__ x, const float* __restrict__ v,
                                               const float* __restrict__ wmu, float* __restrict__ dotv,
                                               float* __restrict__ muv) {
  __shared__ __align__(16) float vl[DIM];
  __shared__ __align__(16) float wm[DIM];
  int bid = blockIdx.x;  // grid 24*144
  int l = bid / 144, n4 = bid % 144;
  int t = threadIdx.x, wid = t >> 6, lane = t & 63;
  for (int i = 0; i < 16; i++) {
    int idx = i * 256 + t;
    vl[idx] = v[(size_t)l * DIM + idx];
    wm[idx] = wmu[idx];
  }
  __syncthreads();
  int n = n4 * 4 + wid;
  const float* row = x + (size_t)(l * NTOK + n) * DIM;
  float ad = 0.f, am = 0.f;
  for (int i = 0; i < 16; i++) {
    int e = i * 256 + lane * 4;
    f32x4 xv = *(const f32x4*)(row + e);
    f32x4 vv = *(const f32x4*)(&vl[e]);
    f32x4 wv = *(const f32x4*)(&wm[e]);
    ad += xv.x * vv.x + xv.y * vv.y + xv.z * vv.z + xv.w * vv.w;
    am += xv.x * wv.x + xv.y * wv.y + xv.z * wv.z + xv.w * wv.w;
  }
  for (int off = 32; off; off >>= 1) { ad += __shfl_down(ad, off, 64); am += __shfl_down(am, off, 64); }
  if (lane == 0) { dotv[l * NTOK + n] = ad; muv[l * NTOK + n] = am; }
}

// ---------------- scores, conf, per-layer top-32 (wave-shuffle argmax) ----------------
__global__ void k_scores(const float* __restrict__ dotv, const float* __restrict__ muv,
                         const float* __restrict__ S2, const float* __restrict__ A, const float* __restrict__ Bv,
                         int* __restrict__ topidx, float* __restrict__ conf) {
  int l = blockIdx.x, t = threadIdx.x;  // grid 24
  __shared__ float raw[NTOK];
  __shared__ float rv[256];
  __shared__ float wv4[4]; __shared__ int wi4[4];
  int wid = t >> 6, lane = t & 63;
  float Al = A[l], Bl = Bv[l];
  for (int j = t; j < NTOK; j += 256) {
    float dv = dotv[l * NTOK + j], mv = muv[l * NTOK + j];
    float var = S2[l * NTOK + j] * (1.0f / DIM) - mv * mv;
    float sd = sqrtf(var + 1e-5f);
    raw[j] = (dv - mv * Al) / sd + Bl;
  }
  __syncthreads();
  float s = 0.f;
  for (int j = t; j < NTOK; j += 256) s += raw[j];
  rv[t] = s; __syncthreads();
  for (int o = 128; o; o >>= 1) { if (t < o) rv[t] += rv[t + o]; __syncthreads(); }
  float mean = rv[0] / NTOK; __syncthreads();
  float qsum = 0.f;
  for (int j = t; j < NTOK; j += 256) { float d = raw[j] - mean; qsum += d * d; }
  rv[t] = qsum; __syncthreads();
  for (int o = 128; o; o >>= 1) { if (t < o) rv[t] += rv[t + o]; __syncthreads(); }
  float sdn = sqrtf(rv[0] / NTOK) + 1e-6f; __syncthreads();
  // iterative top-32 (order invariant under affine normalization; ties -> lowest idx)
  for (int k = 0; k < 32; k++) {
    float bv = -INFINITY; int bi = NTOK;
    for (int j = t; j < NTOK; j += 256) {
      float vv = raw[j];
      if (vv > bv || (vv == bv && j < bi)) { bv = vv; bi = j; }
    }
    for (int off = 32; off; off >>= 1) {
      float ov = __shfl_down(bv, off, 64); int oi = __shfl_down(bi, off, 64);
      if (ov > bv || (ov == bv && oi < bi)) { bv = ov; bi = oi; }
    }
    if (lane == 0) { wv4[wid] = bv; wi4[wid] = bi; }
    __syncthreads();
    if (t == 0) {
      float b2 = wv4[0]; int i2 = wi4[0];
      for (int w2 = 1; w2 < 4; w2++)
        if (wv4[w2] > b2 || (wv4[w2] == b2 && wi4[w2] < i2)) { b2 = wv4[w2]; i2 = wi4[w2]; }
      topidx[l * 32 + k] = i2;
      if (k == 0) conf[l] = (b2 - mean) / sdn;
      raw[i2] = -INFINITY;
    }
    __syncthreads();
  }
}

// ---------------- serial selection logic + alpha softmax ----------------
__global__ void k_select(const float* __restrict__ conf, const int* __restrict__ topidx,
                         const float* __restrict__ logits,
                         int* __restrict__ src, float* __restrict__ alpha) {
  if (threadIdx.x != 0 || blockIdx.x != 0) return;
  float cf[LAY]; for (int l = 0; l < LAY; l++) cf[l] = conf[l];
  bool actt[LAY]; int Mt = 0;
  for (int l = 0; l < LAY; l++) { actt[l] = (l != FOCUSL) && (cf[l] > 3.0f); if (actt[l]) Mt++; }
  bool act[LAY]; int pos[LAY]; int M;
  if (Mt < 8) {
    float cnf[LAY];
    for (int l = 0; l < LAY; l++) cnf[l] = (l == FOCUSL) ? -INFINITY : cf[l];
    bool used[LAY] = {};
    for (int l = 0; l < LAY; l++) { act[l] = false; pos[l] = LAY; }
    for (int j = 0; j < 8; j++) {
      float bv = -INFINITY; int bidx = -1;
      for (int l = 0; l < LAY; l++) if (!used[l] && cnf[l] > bv) { bv = cnf[l]; bidx = l; }
      used[bidx] = true; act[bidx] = true; pos[bidx] = j;
    }
    M = 8;
  } else {
    int c = 0;
    for (int l = 0; l < LAY; l++) { act[l] = actt[l]; if (actt[l]) { pos[l] = c; c++; } else pos[l] = -1; }
    M = Mt;
  }
  int base = 32 / M, rem = 32 - base * M;
  int kk[LAY]; int cum[LAY]; int run = 0;
  for (int l = 0; l < LAY; l++) {
    int k = act[l] ? (base + ((pos[l] < rem) ? 1 : 0)) : 0;
    kk[l] = k; run += k; cum[l] = run;
  }
  for (int tt = 0; tt < 32; tt++) src[tt] = FOCUSL * NTOK + topidx[FOCUSL * 32 + tt];
  for (int tt = 0; tt < 32; tt++) {
    int li = 0;
    while (cum[li] <= tt) li++;
    int r = tt - (cum[li] - kk[li]);
    src[32 + tt] = li * NTOK + topidx[li * 32 + r];
  }
  float mx = -INFINITY;
  for (int l = 0; l < LAY; l++) if (l != FOCUSL && logits[l] > mx) mx = logits[l];
  float ssum = 0.f; float av[LAY];
  for (int l = 0; l < LAY; l++) { av[l] = (l == FOCUSL) ? 0.0f : expf(logits[l] - mx); ssum += av[l]; }
  for (int l = 0; l < LAY; l++) alpha[l] = av[l] / ssum;
}

// ---------------- gather evidence rows ----------------
__global__ void k_gather(const float* __restrict__ x, const int* __restrict__ src, float* __restrict__ out) {
  int b = blockIdx.x, t = threadIdx.x;  // grid 64
  const float* row = x + (size_t)src[b] * DIM;
  float* o = out + (size_t)b * DIM;
  for (int i = 0; i < 4; i++) {
    int e = (i * 256 + t) * 4;
    *(f32x4*)(o + e) = *(const f32x4*)(row + e);
  }
}

// ---------------- group outputs ----------------
__global__ void k_groups(const float* __restrict__ gm, const float* __restrict__ alpha,
                         const float* __restrict__ scale, float* __restrict__ out) {
  int g = blockIdx.x, t = threadIdx.x;  // grid 9
  float sc = scale[0];
  __shared__ float al[LAY];
  if (t < LAY) al[t] = alpha[t];
  __syncthreads();
  for (int i = 0; i < 4; i++) {
    int d = (i * 256 + t) * 4;
    f32x4 mix = {};
    for (int l = 0; l < LAY; l++) {
      f32x4 gv = *(const f32x4*)(gm + ((size_t)(l * 9 + g)) * DIM + d);
      mix += gv * al[l];
    }
    f32x4 anc = *(const f32x4*)(gm + ((size_t)(FOCUSL * 9 + g)) * DIM + d);
    f32x4 o = anc + (mix - anc) * sc;
    *(f32x4*)(out + (size_t)(64 + g) * DIM + d) = o;
  }
}

extern "C" void kernel_launch(void* const* d_in, const int* in_sizes, int n_in,
                              void* d_out, int out_size, void* d_ws, size_t ws_size,
                              hipStream_t stream) {
  const float* tf     = (const float*)d_in[0];
  const float* x      = (const float*)d_in[1];
  const float* W1     = (const float*)d_in[2];
  const float* b1     = (const float*)d_in[3];
  const float* Wc     = (const float*)d_in[4];
  const float* bc_lin = (const float*)d_in[5];
  const float* bc     = (const float*)d_in[6];
  const float* Wi     = (const float*)d_in[7];
  const float* bi_lin = (const float*)d_in[8];
  const float* bi     = (const float*)d_in[9];
  const float* Wf     = (const float*)d_in[10];
  const float* bf_lin = (const float*)d_in[11];
  const float* bf     = (const float*)d_in[12];
  const float* Wq     = (const float*)d_in[13];
  const float* Wk     = (const float*)d_in[14];
  const float* ln_g   = (const float*)d_in[15];
  const float* ln_b   = (const float*)d_in[16];
  const float* logits = (const float*)d_in[17];
  const float* scale  = (const float*)d_in[18];
  float* out = (float*)d_out;

  char* w = (char*)d_ws;
  size_t off = 0;
  auto alloc = [&](size_t bytes) -> void* {
    void* p = w + off;
    off += (bytes + 255) & ~(size_t)255;
    return p;
  };
  // atomic-accumulated buffers first (one memset)
  float* v    = (float*)alloc((size_t)LAY * DIM * 4);
  float* wmu  = (float*)alloc((size_t)DIM * 4);
  size_t zero_bytes = off;
  u16* xb     = (u16*)alloc((size_t)LAY * NTOK * DIM * 2);
  u16* wkb    = (u16*)alloc((size_t)DIM * DIM * 2);
  float* gm   = (float*)alloc((size_t)LAY * 9 * DIM * 4);
  float* y    = (float*)alloc((size_t)LAY * DIM * 4);
  float* tmean= (float*)alloc((size_t)DIM * 4);
  float* tg   = (float*)alloc((size_t)DIM * 4);
  float* pre  = (float*)alloc((size_t)LAY * REDD * 4);
  float* svec = (float*)alloc((size_t)REDD * 4);
  float* cprev= (float*)alloc((size_t)DIM * 4);
  float* uvec = (float*)alloc((size_t)DIM * 4);
  float* ctx  = (float*)alloc((size_t)LAY * DIM * 4);
  float* qpre = (float*)alloc((size_t)LAY * DIM * 4);
  float* h    = (float*)alloc((size_t)LAY * DIM * 4);
  float* A    = (float*)alloc((size_t)LAY * 4);
  float* Bv   = (float*)alloc((size_t)LAY * 4);
  float* s2p  = (float*)alloc((size_t)LAY * NTOK * 64 * 4);
  float* S2   = (float*)alloc((size_t)LAY * NTOK * 4);
  float* dotv = (float*)alloc((size_t)LAY * NTOK * 4);
  float* muv  = (float*)alloc((size_t)LAY * NTOK * 4);
  int* topidx = (int*)alloc((size_t)LAY * 32 * 4);
  float* conf = (float*)alloc((size_t)LAY * 4);
  int* src    = (int*)alloc(64 * 4);
  float* alph = (float*)alloc((size_t)LAY * 4);
  (void)in_sizes; (void)n_in; (void)out_size; (void)ws_size;

  hipMemsetAsync(d_ws, 0, zero_bytes, stream);
  k_text_colmean<<<16, 256, 0, stream>>>(tf, tmean);
  k_text_ln<<<1, 256, 0, stream>>>(tmean, tg);
  k_pass_a<<<576, 128, 0, stream>>>(x, xb, gm);
  k_y<<<96, 256, 0, stream>>>(gm, y);
  k_conv_wk<<<16384, 256, 0, stream>>>(Wk, wkb);
  k_gemm_s2<<<108 * 32, 256, 0, stream>>>(xb, wkb, s2p);
  k_s2_reduce<<<54, 256, 0, stream>>>(s2p, S2);
  k_pre<<<1024, 256, 0, stream>>>(W1, b1, y, tg, pre);
  k_dsu_init<<<16, 256, 0, stream>>>(cprev, uvec);
  for (int l = 0; l < LAY; l++) {
    k_dsu1<<<256, 256, 0, stream>>>(W1, pre, uvec, svec, l);
    k_dsu2<<<1024, 256, 0, stream>>>(Wc, Wi, Wf, bc_lin, bc, bi_lin, bi, bf_lin, bf,
                                     svec, cprev, uvec, ctx, l);
  }
  k_qpre<<<1024, 256, 0, stream>>>(ctx, Wq, qpre);
  k_qln<<<24, 256, 0, stream>>>(qpre, ln_g, ln_b, h, A, Bv);
  k_v<<<256, 256, 0, stream>>>(Wk, h, v, wmu);
  k_dotmu<<<24 * 144, 256, 0, stream>>>(x, v, wmu, dotv, muv);
  k_scores<<<24, 256, 0, stream>>>(dotv, muv, S2, A, Bv, topidx, conf);
  k_select<<<1, 64, 0, stream>>>(conf, topidx, logits, src, alph);
  k_gather<<<64, 256, 0, stream>>>(x, src, out);
  k_groups<<<9, 256, 0, stream>>>(gm, alph, scale, out);
}